// Round 6
// baseline (271.313 us; speedup 1.0000x reference)
//
#include <hip/hip_runtime.h>
#include <hip/hip_bf16.h>

typedef __attribute__((ext_vector_type(8))) short bf16x8;
typedef __attribute__((ext_vector_type(4))) float f32x4;

#define DEV static __device__ __forceinline__

DEV unsigned short f2bf(float f) {
    __hip_bfloat16 h = __float2bfloat16(f);
    return __builtin_bit_cast(unsigned short, h);
}
DEV float bf2f(unsigned short s) {
    union { unsigned int u; float f; } v; v.u = ((unsigned int)s) << 16; return v.f;
}
DEV bf16x8 ld_bf8(const unsigned short* p) { return *reinterpret_cast<const bf16x8*>(p); }
DEV f32x4 mfma16(bf16x8 a, bf16x8 b, f32x4 c) {
    return __builtin_amdgcn_mfma_f32_16x16x32_bf16(a, b, c, 0, 0, 0);
}
// 8x8 weight fragment, K padded 8->32, M/N padded 8->16: lane li (lg==0) holds row li.
DEV bf16x8 make_wfrag(const float* wmat, int li, int lg, float scale) {
    bf16x8 f = {};
    if (lg == 0 && li < 8) {
        #pragma unroll
        for (int t = 0; t < 8; t++) f[t] = (short)f2bf(wmat[li*8 + t] * scale);
    }
    return f;
}

// ---------------- K1: qkv GEMM + bias + RoPE (f32 inputs, cvt fused in staging) ----
__global__ __launch_bounds__(256) void k_qkv(
    const float* __restrict__ xf, const float* __restrict__ wf,
    const float* __restrict__ bias,
    unsigned short* __restrict__ Qb, unsigned short* __restrict__ Kb,
    unsigned short* __restrict__ Vt)
{
    __shared__ unsigned short As[64][40];
    __shared__ unsigned short Bs[64][40];
    const int m0 = blockIdx.x * 64, c0 = blockIdx.y * 64;
    const int t = threadIdx.x;
    const int w = t >> 6, lane = t & 63, li = lane & 15, lg = lane >> 4;
    const int wr = w >> 1, wc = w & 1;
    f32x4 acc[2][2] = {};
    const int srow = t >> 2, spart = (t & 3) * 8;
    for (int kt = 0; kt < 512; kt += 32) {
        const float* xs = &xf[(size_t)(m0 + srow) * 512 + kt + spart];
        float4 a0 = *(const float4*)xs, a1 = *(const float4*)(xs + 4);
        const float* wsrc = &wf[(size_t)(c0 + srow) * 512 + kt + spart];
        float4 b0 = *(const float4*)wsrc, b1 = *(const float4*)(wsrc + 4);
        ushort4 ua0 = { f2bf(a0.x), f2bf(a0.y), f2bf(a0.z), f2bf(a0.w) };
        ushort4 ua1 = { f2bf(a1.x), f2bf(a1.y), f2bf(a1.z), f2bf(a1.w) };
        ushort4 ub0 = { f2bf(b0.x), f2bf(b0.y), f2bf(b0.z), f2bf(b0.w) };
        ushort4 ub1 = { f2bf(b1.x), f2bf(b1.y), f2bf(b1.z), f2bf(b1.w) };
        *(ushort4*)&As[srow][spart] = ua0; *(ushort4*)&As[srow][spart + 4] = ua1;
        *(ushort4*)&Bs[srow][spart] = ub0; *(ushort4*)&Bs[srow][spart + 4] = ub1;
        __syncthreads();
        bf16x8 af[2], bfr[2];
        #pragma unroll
        for (int mf = 0; mf < 2; mf++) af[mf] = ld_bf8(&As[wr*32 + mf*16 + li][lg*8]);
        #pragma unroll
        for (int nf = 0; nf < 2; nf++) bfr[nf] = ld_bf8(&Bs[wc*32 + nf*16 + li][lg*8]);
        #pragma unroll
        for (int mf = 0; mf < 2; mf++)
            #pragma unroll
            for (int nf = 0; nf < 2; nf++)
                acc[mf][nf] = mfma16(af[mf], bfr[nf], acc[mf][nf]);
        __syncthreads();
    }
    const int type = c0 >> 9;
    const int head = (c0 & 511) >> 6;
    const float b0s = bias[c0 + wc*32 + li];
    const float b1s = bias[c0 + wc*32 + 16 + li];
    float invf = 0.f;
    if (type < 2) invf = powf(10000.f, -(float)li * (1.f/16.f));
    #pragma unroll
    for (int mf = 0; mf < 2; mf++) {
        #pragma unroll
        for (int r = 0; r < 4; r++) {
            int grow = m0 + wr*32 + mf*16 + lg*4 + r;
            int tok = grow & 2047, bb = grow >> 11;
            float v0 = acc[mf][0][r] + b0s;
            float v1 = acc[mf][1][r] + b1s;
            if (type < 2) {
                float ang = (wc == 0 ? (float)(tok & 255) : (float)(tok >> 8)) * invf;
                float s, c;
                sincosf(ang, &s, &c);
                float r0 = v0 * c - v1 * s;
                float r1 = v0 * s + v1 * c;
                unsigned short* dst = (type == 0 ? Qb : Kb);
                size_t base = (((size_t)(bb*8 + head)) * 2048 + tok) * 64 + wc*32 + li;
                dst[base]      = f2bf(r0);
                dst[base + 16] = f2bf(r1);
            } else {
                size_t base = (((size_t)(bb*8 + head)) * 64 + wc*32 + li) * 2048 + tok;
                Vt[base]             = f2bf(v0);
                Vt[base + 16 * 2048] = f2bf(v1);
            }
        }
    }
}

// shared macros for the attention kernels -------------------------------------
#define JC(x) (jh*1024 + ((x) > 15 ? 15 : (x))*64)

#define LOADK(JX) do { const int j0_ = (JX); \
    _Pragma("unroll") for (int nf = 0; nf < 4; nf++) { \
        const unsigned short* kp_ = Kp + (size_t)(j0_ + nf*16 + li) * 64; \
        kf[nf*2]   = ld_bf8(kp_ + lg*8); \
        kf[nf*2+1] = ld_bf8(kp_ + 32 + lg*8); } \
} while (0)

#define LOADV(JX) do { const int j0_ = (JX); \
    _Pragma("unroll") for (int nf = 0; nf < 4; nf++) { \
        const unsigned short* vp_ = Vp + (size_t)(nf*16 + li) * 2048 + j0_; \
        vf[nf*2]   = ld_bf8(vp_ + lg*8); \
        vf[nf*2+1] = ld_bf8(vp_ + 32 + lg*8); } \
} while (0)

#define QKW(LTW) do { \
    f32x4 sq0 = {}, sq1 = {}, sq2 = {}, sq3 = {}; \
    sq0 = mfma16(qa0, kf[0], sq0); sq0 = mfma16(qa1, kf[1], sq0); \
    sq1 = mfma16(qa0, kf[2], sq1); sq1 = mfma16(qa1, kf[3], sq1); \
    sq2 = mfma16(qa0, kf[4], sq2); sq2 = mfma16(qa1, kf[5], sq2); \
    sq3 = mfma16(qa0, kf[6], sq3); sq3 = mfma16(qa1, kf[7], sq3); \
    _Pragma("unroll") for (int r = 0; r < 4; r++) { \
        LTW[((lg*4 + r)*64 +  0 + li)*8 + w] = f2bf(sq0[r]); \
        LTW[((lg*4 + r)*64 + 16 + li)*8 + w] = f2bf(sq1[r]); \
        LTW[((lg*4 + r)*64 + 32 + li)*8 + w] = f2bf(sq2[r]); \
        LTW[((lg*4 + r)*64 + 48 + li)*8 + w] = f2bf(sq3[r]); } \
} while (0)

#define MIX(LTR) do { \
    _Pragma("unroll") for (int x = 0; x < 2; x++) { \
        const int i2 = 2*w + x; f32x4 invl = x ? invlB : invlA; \
        _Pragma("unroll") for (int jj = 0; jj < 4; jj++) { \
            const int e0 = i2*64 + jj*16; \
            bf16x8 bfv = {}; \
            if (lg == 0) bfv = *(const bf16x8*)&LTR[(e0 + li)*8]; \
            f32x4 d = mfma16(W1f, bfv, zero); \
            float p0 = exp2f(d[0]) * invl[0], p1 = exp2f(d[1]) * invl[1]; \
            float p2 = exp2f(d[2]) * invl[2], p3 = exp2f(d[3]) * invl[3]; \
            unsigned lo = (unsigned)f2bf(p0) | ((unsigned)f2bf(p1) << 16); \
            unsigned hi = (unsigned)f2bf(p2) | ((unsigned)f2bf(p3) << 16); \
            unsigned plo = (unsigned)__shfl_xor((int)lo, 16); \
            unsigned phi = (unsigned)__shfl_xor((int)hi, 16); \
            union { unsigned u[4]; bf16x8 v; } af_; \
            af_.u[0] = lo; af_.u[1] = hi; af_.u[2] = plo; af_.u[3] = phi; \
            f32x4 a2 = mfma16(af_.v, W2f, zero); \
            if (li < 8) { \
                ushort4 o = { f2bf(a2[0]), f2bf(a2[1]), f2bf(a2[2]), f2bf(a2[3]) }; \
                *(ushort4*)&Ah[li*1168 + i2*72 + jj*16 + lg*4] = o; } \
        } } \
} while (0)

#define PVOP() do { \
    _Pragma("unroll") for (int kk = 0; kk < 2; kk++) { \
        bf16x8 pa = *(const bf16x8*)&Ah[w*1168 + li*72 + kk*32 + lg*8]; \
        oacc[0] = mfma16(pa, vf[0 + kk], oacc[0]); \
        oacc[1] = mfma16(pa, vf[2 + kk], oacc[1]); \
        oacc[2] = mfma16(pa, vf[4 + kk], oacc[2]); \
        oacc[3] = mfma16(pa, vf[6 + kk], oacc[3]); } \
} while (0)

#define SUMEXP(LTR) do { \
    _Pragma("unroll") for (int x = 0; x < 2; x++) { \
        const int i2 = 2*w + x; float s_ = 0.f; \
        _Pragma("unroll") for (int jj = 0; jj < 4; jj++) { \
            const int e0 = i2*64 + jj*16; \
            bf16x8 bfv = {}; \
            if (lg == 0) bfv = *(const bf16x8*)&LTR[(e0 + li)*8]; \
            f32x4 d = mfma16(bfv, W1f, zero); \
            s_ += (exp2f(d[0]) + exp2f(d[1])) + (exp2f(d[2]) + exp2f(d[3])); } \
        if (x == 0) lacc0 += s_; else lacc1 += s_; } \
} while (0)

// ---------------- K2: pass 1 — l = sum_j exp(premixed logits), pipelined --------
__global__ __launch_bounds__(512, 4) void k_lsum(
    const unsigned short* __restrict__ Qb, const unsigned short* __restrict__ Kb,
    const float* __restrict__ w_pre, float* __restrict__ Lp)
{
    __shared__ unsigned short LtA[8192];
    __shared__ unsigned short LtB[8192];
    const int orig = blockIdx.x;
    const int virt = ((orig & 7) << 6) | (orig >> 3);
    const int jh = virt & 1, it = (virt >> 1) & 127, bb = virt >> 8;
    const int i0 = it * 16;
    const int tid = threadIdx.x, w = tid >> 6, lane = tid & 63, li = lane & 15, lg = lane >> 4;
    bf16x8 W1f = make_wfrag(w_pre, li, lg, 0.125f * 1.44269504088896340736f);
    const unsigned short* Qp = Qb + (((size_t)(bb*8 + w)) * 2048 + i0 + li) * 64;
    bf16x8 qa0 = ld_bf8(Qp + lg*8), qa1 = ld_bf8(Qp + 32 + lg*8);
    const unsigned short* Kp = Kb + ((size_t)(bb*8 + w)) * 2048 * 64;
    const f32x4 zero = {};
    bf16x8 kf[8];
    LOADK(JC(0));
    QKW(LtA);
    LOADK(JC(1));
    __syncthreads();
    float lacc0 = 0.f, lacc1 = 0.f;
    #pragma unroll 1
    for (int tt = 0; tt < 8; tt++) {
        // even t = 2tt: read LtA, write LtB
        QKW(LtB);
        SUMEXP(LtA);
        LOADK(JC(2*tt + 2));
        __syncthreads();
        // odd t = 2tt+1: read LtB, write LtA
        if (tt < 7) { QKW(LtA); }
        SUMEXP(LtB);
        if (tt < 7) { LOADK(JC(2*tt + 3)); }
        __syncthreads();
    }
    lacc0 += __shfl_xor(lacc0, 16); lacc0 += __shfl_xor(lacc0, 32);
    lacc1 += __shfl_xor(lacc1, 16); lacc1 += __shfl_xor(lacc1, 32);
    if (lg == 0 && li < 8) {
        float* Lpw = Lp + (size_t)jh * 32768;
        size_t base = (size_t)bb*2048 + i0;
        Lpw[(base + 2*w + 0)*8 + li] = lacc0;
        Lpw[(base + 2*w + 1)*8 + li] = lacc1;
    }
}

// ---------------- K3: pass 2 — pipelined QK || mix, PV || prefetch --------
__global__ __launch_bounds__(512, 4) void k_attn(
    const unsigned short* __restrict__ Qb, const unsigned short* __restrict__ Kb,
    const unsigned short* __restrict__ Vt,
    const float* __restrict__ w_pre, const float* __restrict__ w_post,
    const float* __restrict__ Lp,
    unsigned short* __restrict__ AOp0, unsigned short* __restrict__ AOp1)
{
    __shared__ unsigned short LtA[8192];
    __shared__ unsigned short LtB[8192];
    __shared__ unsigned short Ah[8 * 1168];
    __shared__ float Llds[128];
    const int orig = blockIdx.x;
    const int virt = ((orig & 7) << 6) | (orig >> 3);
    const int jh = virt & 1, it = (virt >> 1) & 127, bb = virt >> 8;
    const int i0 = it * 16;
    const int tid = threadIdx.x, w = tid >> 6, lane = tid & 63, li = lane & 15, lg = lane >> 4;
    bf16x8 W1f = make_wfrag(w_pre, li, lg, 0.125f * 1.44269504088896340736f);
    bf16x8 W2f = make_wfrag(w_post, li, lg, 1.0f);
    if (tid < 128) {
        size_t g = ((size_t)bb*2048 + i0 + (tid >> 3)) * 8 + (tid & 7);
        Llds[tid] = 1.0f / (Lp[g] + Lp[32768 + g]);
    }
    const unsigned short* Qp = Qb + (((size_t)(bb*8 + w)) * 2048 + i0 + li) * 64;
    bf16x8 qa0 = ld_bf8(Qp + lg*8), qa1 = ld_bf8(Qp + 32 + lg*8);
    const unsigned short* Kp = Kb + ((size_t)(bb*8 + w)) * 2048 * 64;
    const unsigned short* Vp = Vt + ((size_t)(bb*8 + w)) * 64 * 2048;
    const f32x4 zero = {};
    bf16x8 kf[8], vf[8];
    LOADK(JC(0));
    LOADV(JC(0));
    QKW(LtA);
    LOADK(JC(1));
    __syncthreads();
    const int lgc = lg & 1;
    f32x4 invlA = *(const f32x4*)&Llds[(2*w + 0)*8 + lgc*4];
    f32x4 invlB = *(const f32x4*)&Llds[(2*w + 1)*8 + lgc*4];
    f32x4 oacc[4] = {};
    #pragma unroll 1
    for (int tt = 0; tt < 8; tt++) {
        // even t = 2tt: Lt read A / write B
        QKW(LtB);               // QK(t+1), K regs prefetched
        MIX(LtA);               // premix+exp+postmix(t) -> Ah
        __syncthreads();
        PVOP();                 // PV(t) from Ah + vf
        LOADV(JC(2*tt + 1));
        LOADK(JC(2*tt + 2));
        __syncthreads();
        // odd t = 2tt+1: Lt read B / write A
        if (tt < 7) { QKW(LtA); }
        MIX(LtB);
        __syncthreads();
        PVOP();
        if (tt < 7) { LOADV(JC(2*tt + 2)); LOADK(JC(2*tt + 3)); }
        __syncthreads();
    }
    unsigned short* ao = jh ? AOp1 : AOp0;
    #pragma unroll
    for (int nf = 0; nf < 4; nf++)
        #pragma unroll
        for (int r = 0; r < 4; r++)
            ao[((size_t)bb*2048 + i0 + lg*4 + r)*512 + w*64 + nf*16 + li] = f2bf(oacc[nf][r]);
}

// ---------------- K4: output GEMM, partial-sum + f32-weight cvt fused --------
__global__ __launch_bounds__(256) void k_out(
    const unsigned short* __restrict__ a0, const unsigned short* __restrict__ a1,
    const float* __restrict__ wf, const float* __restrict__ bias,
    float* __restrict__ out)
{
    __shared__ unsigned short As[64][40];
    __shared__ unsigned short Bs[64][40];
    const int m0 = blockIdx.x * 64, c0 = blockIdx.y * 64;
    const int t = threadIdx.x;
    const int w = t >> 6, lane = t & 63, li = lane & 15, lg = lane >> 4;
    const int wr = w >> 1, wc = w & 1;
    f32x4 acc[2][2] = {};
    const int srow = t >> 2, spart = (t & 3) * 8;
    for (int kt = 0; kt < 512; kt += 32) {
        size_t aidx = (size_t)(m0 + srow) * 512 + kt + spart;
        uint4 ua = *(const uint4*)&a0[aidx];
        uint4 ub = *(const uint4*)&a1[aidx];
        const unsigned short* pa = (const unsigned short*)&ua;
        const unsigned short* pb = (const unsigned short*)&ub;
        unsigned short us[8];
        #pragma unroll
        for (int q = 0; q < 8; q++) us[q] = f2bf(bf2f(pa[q]) + bf2f(pb[q]));
        *reinterpret_cast<uint4*>(&As[srow][spart]) = *(const uint4*)us;
        const float* wsrc = &wf[(size_t)(c0 + srow) * 512 + kt + spart];
        float4 b0 = *(const float4*)wsrc, b1 = *(const float4*)(wsrc + 4);
        ushort4 ub0 = { f2bf(b0.x), f2bf(b0.y), f2bf(b0.z), f2bf(b0.w) };
        ushort4 ub1 = { f2bf(b1.x), f2bf(b1.y), f2bf(b1.z), f2bf(b1.w) };
        *(ushort4*)&Bs[srow][spart] = ub0; *(ushort4*)&Bs[srow][spart + 4] = ub1;
        __syncthreads();
        bf16x8 af[2], bfr[2];
        #pragma unroll
        for (int mf = 0; mf < 2; mf++) af[mf] = ld_bf8(&As[wr*32 + mf*16 + li][lg*8]);
        #pragma unroll
        for (int nf = 0; nf < 2; nf++) bfr[nf] = ld_bf8(&Bs[wc*32 + nf*16 + li][lg*8]);
        #pragma unroll
        for (int mf = 0; mf < 2; mf++)
            #pragma unroll
            for (int nf = 0; nf < 2; nf++)
                acc[mf][nf] = mfma16(af[mf], bfr[nf], acc[mf][nf]);
        __syncthreads();
    }
    #pragma unroll
    for (int mf = 0; mf < 2; mf++)
        #pragma unroll
        for (int nf = 0; nf < 2; nf++)
            #pragma unroll
            for (int r = 0; r < 4; r++) {
                int grow = m0 + wr*32 + mf*16 + lg*4 + r;
                int gcol = c0 + wc*32 + nf*16 + li;
                out[(size_t)grow * 512 + gcol] = acc[mf][nf][r] + bias[gcol];
            }
}

extern "C" void kernel_launch(void* const* d_in, const int* in_sizes, int n_in,
                              void* d_out, int out_size, void* d_ws, size_t ws_size,
                              hipStream_t stream)
{
    const float* x      = (const float*)d_in[0];
    const float* w_qkv  = (const float*)d_in[1];
    const float* b_qkv  = (const float*)d_in[2];
    const float* w_pre  = (const float*)d_in[3];
    const float* w_post = (const float*)d_in[4];
    const float* w_out  = (const float*)d_in[5];
    const float* b_out  = (const float*)d_in[6];
    float* out = (float*)d_out;

    char* ws = (char*)d_ws;
    unsigned short* Qb   = (unsigned short*)(ws);               // 4 MB
    unsigned short* Kb   = (unsigned short*)(ws + 4194304);     // 4 MB
    unsigned short* Vt   = (unsigned short*)(ws + 8388608);     // 4 MB
    unsigned short* AOp0 = (unsigned short*)(ws + 12582912);    // 4 MB
    unsigned short* AOp1 = (unsigned short*)(ws + 16777216);    // 4 MB
    float* Lp            = (float*)(ws + 20971520);             // 256 KB

    k_qkv<<<dim3(64, 24), 256, 0, stream>>>(x, w_qkv, b_qkv, Qb, Kb, Vt);
    k_lsum<<<512, 512, 0, stream>>>(Qb, Kb, w_pre, Lp);
    k_attn<<<512, 512, 0, stream>>>(Qb, Kb, Vt, w_pre, w_post, Lp, AOp0, AOp1);
    k_out<<<dim3(64, 8), 256, 0, stream>>>(AOp0, AOp1, w_out, b_out, out);
}

// Round 8
// 247.293 us; speedup vs baseline: 1.0971x; 1.0971x over previous
//
#include <hip/hip_runtime.h>
#include <hip/hip_bf16.h>

typedef __attribute__((ext_vector_type(8))) short bf16x8;
typedef __attribute__((ext_vector_type(4))) float f32x4;

#define DEV static __device__ __forceinline__

DEV unsigned short f2bf(float f) {
    __hip_bfloat16 h = __float2bfloat16(f);
    return __builtin_bit_cast(unsigned short, h);
}
DEV float bf2f(unsigned short s) {
    union { unsigned int u; float f; } v; v.u = ((unsigned int)s) << 16; return v.f;
}
DEV bf16x8 ld_bf8(const unsigned short* p) { return *reinterpret_cast<const bf16x8*>(p); }
DEV f32x4 mfma16(bf16x8 a, bf16x8 b, f32x4 c) {
    return __builtin_amdgcn_mfma_f32_16x16x32_bf16(a, b, c, 0, 0, 0);
}

// ---------------- K1: qkv GEMM + bias + RoPE (r6-validated) ----------------
__global__ __launch_bounds__(256) void k_qkv(
    const float* __restrict__ xf, const float* __restrict__ wf,
    const float* __restrict__ bias,
    unsigned short* __restrict__ Qb, unsigned short* __restrict__ Kb,
    unsigned short* __restrict__ Vt)
{
    __shared__ unsigned short As[64][40];
    __shared__ unsigned short Bs[64][40];
    const int m0 = blockIdx.x * 64, c0 = blockIdx.y * 64;
    const int t = threadIdx.x;
    const int w = t >> 6, lane = t & 63, li = lane & 15, lg = lane >> 4;
    const int wr = w >> 1, wc = w & 1;
    f32x4 acc[2][2] = {};
    const int srow = t >> 2, spart = (t & 3) * 8;
    for (int kt = 0; kt < 512; kt += 32) {
        const float* xs = &xf[(size_t)(m0 + srow) * 512 + kt + spart];
        float4 a0 = *(const float4*)xs, a1 = *(const float4*)(xs + 4);
        const float* wsrc = &wf[(size_t)(c0 + srow) * 512 + kt + spart];
        float4 b0 = *(const float4*)wsrc, b1 = *(const float4*)(wsrc + 4);
        ushort4 ua0 = { f2bf(a0.x), f2bf(a0.y), f2bf(a0.z), f2bf(a0.w) };
        ushort4 ua1 = { f2bf(a1.x), f2bf(a1.y), f2bf(a1.z), f2bf(a1.w) };
        ushort4 ub0 = { f2bf(b0.x), f2bf(b0.y), f2bf(b0.z), f2bf(b0.w) };
        ushort4 ub1 = { f2bf(b1.x), f2bf(b1.y), f2bf(b1.z), f2bf(b1.w) };
        *(ushort4*)&As[srow][spart] = ua0; *(ushort4*)&As[srow][spart + 4] = ua1;
        *(ushort4*)&Bs[srow][spart] = ub0; *(ushort4*)&Bs[srow][spart + 4] = ub1;
        __syncthreads();
        bf16x8 af[2], bfr[2];
        #pragma unroll
        for (int mf = 0; mf < 2; mf++) af[mf] = ld_bf8(&As[wr*32 + mf*16 + li][lg*8]);
        #pragma unroll
        for (int nf = 0; nf < 2; nf++) bfr[nf] = ld_bf8(&Bs[wc*32 + nf*16 + li][lg*8]);
        #pragma unroll
        for (int mf = 0; mf < 2; mf++)
            #pragma unroll
            for (int nf = 0; nf < 2; nf++)
                acc[mf][nf] = mfma16(af[mf], bfr[nf], acc[mf][nf]);
        __syncthreads();
    }
    const int type = c0 >> 9;
    const int head = (c0 & 511) >> 6;
    const float b0s = bias[c0 + wc*32 + li];
    const float b1s = bias[c0 + wc*32 + 16 + li];
    float invf = 0.f;
    if (type < 2) invf = powf(10000.f, -(float)li * (1.f/16.f));
    #pragma unroll
    for (int mf = 0; mf < 2; mf++) {
        #pragma unroll
        for (int r = 0; r < 4; r++) {
            int grow = m0 + wr*32 + mf*16 + lg*4 + r;
            int tok = grow & 2047, bb = grow >> 11;
            float v0 = acc[mf][0][r] + b0s;
            float v1 = acc[mf][1][r] + b1s;
            if (type < 2) {
                float ang = (wc == 0 ? (float)(tok & 255) : (float)(tok >> 8)) * invf;
                float s, c;
                sincosf(ang, &s, &c);
                float r0 = v0 * c - v1 * s;
                float r1 = v0 * s + v1 * c;
                unsigned short* dst = (type == 0 ? Qb : Kb);
                size_t base = (((size_t)(bb*8 + head)) * 2048 + tok) * 64 + wc*32 + li;
                dst[base]      = f2bf(r0);
                dst[base + 16] = f2bf(r1);
            } else {
                size_t base = (((size_t)(bb*8 + head)) * 64 + wc*32 + li) * 2048 + tok;
                Vt[base]             = f2bf(v0);
                Vt[base + 16 * 2048] = f2bf(v1);
            }
        }
    }
}

#define SCALE_L2E (0.125f * 1.44269504088896340736f)

// Stage Q tile for all 8 heads into LDS: Qlds[h][16 i][72 pad]
#define STAGE_Q() do { \
    for (int v = threadIdx.x; v < 1024; v += 512) { \
        int h_ = v >> 7, rest_ = v & 127, i_ = rest_ >> 3, ch_ = rest_ & 7; \
        *(uint4*)&Qlds[h_][i_][ch_*8] = \
            *(const uint4*)&Qb[(((size_t)(bb*8 + h_))*2048 + i0 + i_)*64 + ch_*8]; \
    } \
} while (0)

// QK^T for all 8 heads: lane holds (j = js+li, i = lg*4+r), acc[h][r]
#define QK_ALLH() do { \
    _Pragma("unroll") for (int h = 0; h < 8; h++) { \
        const unsigned short* kp_ = Kb + (((size_t)(bb*8 + h))*2048 + js + li)*64; \
        bf16x8 k0_ = ld_bf8(kp_ + lg*8), k1_ = ld_bf8(kp_ + 32 + lg*8); \
        bf16x8 q0_ = ld_bf8(&Qlds[h][li][lg*8]); \
        bf16x8 q1_ = ld_bf8(&Qlds[h][li][32 + lg*8]); \
        f32x4 z_ = {}; \
        z_ = mfma16(q0_, k0_, z_); \
        acc[h] = mfma16(q1_, k1_, z_); \
    } \
} while (0)

// ---------------- K2: pass 1 — l[a][i] = sum_j exp2(premix(QK)) ----------------
// Each wave covers a 16-j slice; per-wave partials reduced across waves via LDS.
__global__ __launch_bounds__(512, 4) void k_lsum(
    const unsigned short* __restrict__ Qb, const unsigned short* __restrict__ Kb,
    const float* __restrict__ w_pre, float* __restrict__ Lp)
{
    __shared__ unsigned short Qlds[8][16][72];
    __shared__ float Red[8][128];
    const int orig = blockIdx.x;
    const int virt = ((orig & 7) << 6) | (orig >> 3);
    const int jh = virt & 1, it = (virt >> 1) & 127, bb = virt >> 8;
    const int i0 = it * 16;
    const int tid = threadIdx.x, w = tid >> 6, lane = tid & 63, li = lane & 15, lg = lane >> 4;
    STAGE_Q();
    __syncthreads();
    float lacc[4][8] = {};
    #pragma unroll 1
    for (int s = 0; s < 8; s++) {
        const int js = jh*1024 + s*128 + w*16;
        f32x4 acc[8];
        QK_ALLH();
        #pragma unroll
        for (int r = 0; r < 4; r++) {
            #pragma unroll
            for (int a = 0; a < 8; a++) {
                float t = 0.f;
                #pragma unroll
                for (int h = 0; h < 8; h++) t = fmaf(w_pre[a*8 + h], acc[h][r], t);
                lacc[r][a] += __builtin_amdgcn_exp2f(t * SCALE_L2E);
            }
        }
    }
    // reduce over the 16 j-lanes (li bits 0..3)
    #pragma unroll
    for (int m = 1; m <= 8; m <<= 1)
        #pragma unroll
        for (int r = 0; r < 4; r++)
            #pragma unroll
            for (int a = 0; a < 8; a++)
                lacc[r][a] += __shfl_xor(lacc[r][a], m);
    // cross-wave reduction: each wave holds only its 128-j partial
    if (li == 0) {
        #pragma unroll
        for (int r = 0; r < 4; r++)
            #pragma unroll
            for (int a = 0; a < 8; a++)
                Red[w][(lg*4 + r)*8 + a] = lacc[r][a];
    }
    __syncthreads();
    if (tid < 128) {
        float s = 0.f;
        #pragma unroll
        for (int ww = 0; ww < 8; ww++) s += Red[ww][tid];
        float* Lpw = Lp + (size_t)jh * 32768;
        Lpw[((size_t)bb*2048 + i0 + (tid >> 3))*8 + (tid & 7)] = s;
    }
}

// ---------------- K3: pass 2 — lane-local mix, LDS only for the (i,j) transpose ----
__global__ __launch_bounds__(512, 4) void k_attn(
    const unsigned short* __restrict__ Qb, const unsigned short* __restrict__ Kb,
    const unsigned short* __restrict__ Vt,
    const float* __restrict__ w_pre, const float* __restrict__ w_post,
    const float* __restrict__ Lp,
    unsigned short* __restrict__ AOp0, unsigned short* __restrict__ AOp1)
{
    __shared__ unsigned short Qlds[8][16][72];
    __shared__ unsigned short Ah[8][16][136];   // [c][i][j 128 + pad]
    __shared__ float Llds[128];                 // log2(l)[a][i16]
    const int orig = blockIdx.x;
    const int virt = ((orig & 7) << 6) | (orig >> 3);
    const int jh = virt & 1, it = (virt >> 1) & 127, bb = virt >> 8;
    const int i0 = it * 16;
    const int tid = threadIdx.x, w = tid >> 6, lane = tid & 63, li = lane & 15, lg = lane >> 4;
    STAGE_Q();
    if (tid < 128) {
        int i_ = tid >> 3, a_ = tid & 7;
        size_t g = ((size_t)bb*2048 + i0 + i_)*8 + a_;
        Llds[a_*16 + i_] = __builtin_amdgcn_logf(Lp[g] + Lp[32768 + g]);
    }
    const unsigned short* Vp = Vt + ((size_t)(bb*8 + w)) * 64 * 2048;
    __syncthreads();
    f32x4 oacc[4] = {};
    #pragma unroll 1
    for (int s = 0; s < 8; s++) {
        const int j0 = jh*1024 + s*128;
        const int js = j0 + w*16;
        f32x4 acc[8];
        QK_ALLH();
        // PV of previous step (Ah holds step s-1)
        if (s > 0) {
            const int jp = j0 - 128;
            #pragma unroll
            for (int kc = 0; kc < 4; kc++) {
                bf16x8 pa = ld_bf8(&Ah[w][li][kc*32 + lg*8]);
                #pragma unroll
                for (int nf = 0; nf < 4; nf++) {
                    bf16x8 vfr = ld_bf8(Vp + (size_t)(nf*16 + li)*2048 + jp + kc*32 + lg*8);
                    oacc[nf] = mfma16(pa, vfr, oacc[nf]);
                }
            }
        }
        // lane-local premix -> exp2 (normalized) -> postmix
        unsigned short a2s[4][8];
        #pragma unroll
        for (int r = 0; r < 4; r++) {
            float p[8];
            #pragma unroll
            for (int a = 0; a < 8; a++) {
                float t = 0.f;
                #pragma unroll
                for (int h = 0; h < 8; h++) t = fmaf(w_pre[a*8 + h], acc[h][r], t);
                p[a] = __builtin_amdgcn_exp2f(t * SCALE_L2E - Llds[a*16 + lg*4 + r]);
            }
            #pragma unroll
            for (int c = 0; c < 8; c++) {
                float t = 0.f;
                #pragma unroll
                for (int a = 0; a < 8; a++) t = fmaf(w_post[c*8 + a], p[a], t);
                a2s[r][c] = f2bf(t);
            }
        }
        __syncthreads();   // all waves' PV reads of Ah[s-1] done
        #pragma unroll
        for (int r = 0; r < 4; r++)
            #pragma unroll
            for (int c = 0; c < 8; c++)
                Ah[c][lg*4 + r][w*16 + li] = a2s[r][c];
        __syncthreads();   // Ah[s] complete
    }
    // final PV (step 7)
    {
        const int jp = jh*1024 + 7*128;
        #pragma unroll
        for (int kc = 0; kc < 4; kc++) {
            bf16x8 pa = ld_bf8(&Ah[w][li][kc*32 + lg*8]);
            #pragma unroll
            for (int nf = 0; nf < 4; nf++) {
                bf16x8 vfr = ld_bf8(Vp + (size_t)(nf*16 + li)*2048 + jp + kc*32 + lg*8);
                oacc[nf] = mfma16(pa, vfr, oacc[nf]);
            }
        }
    }
    unsigned short* ao = jh ? AOp1 : AOp0;
    #pragma unroll
    for (int nf = 0; nf < 4; nf++)
        #pragma unroll
        for (int r = 0; r < 4; r++)
            ao[((size_t)bb*2048 + i0 + lg*4 + r)*512 + w*64 + nf*16 + li] = f2bf(oacc[nf][r]);
}

// ---------------- K4: output GEMM, partial-sum + f32-weight cvt fused (r6-validated)
__global__ __launch_bounds__(256) void k_out(
    const unsigned short* __restrict__ a0, const unsigned short* __restrict__ a1,
    const float* __restrict__ wf, const float* __restrict__ bias,
    float* __restrict__ out)
{
    __shared__ unsigned short As[64][40];
    __shared__ unsigned short Bs[64][40];
    const int m0 = blockIdx.x * 64, c0 = blockIdx.y * 64;
    const int t = threadIdx.x;
    const int w = t >> 6, lane = t & 63, li = lane & 15, lg = lane >> 4;
    const int wr = w >> 1, wc = w & 1;
    f32x4 acc[2][2] = {};
    const int srow = t >> 2, spart = (t & 3) * 8;
    for (int kt = 0; kt < 512; kt += 32) {
        size_t aidx = (size_t)(m0 + srow) * 512 + kt + spart;
        uint4 ua = *(const uint4*)&a0[aidx];
        uint4 ub = *(const uint4*)&a1[aidx];
        const unsigned short* pa = (const unsigned short*)&ua;
        const unsigned short* pb = (const unsigned short*)&ub;
        unsigned short us[8];
        #pragma unroll
        for (int q = 0; q < 8; q++) us[q] = f2bf(bf2f(pa[q]) + bf2f(pb[q]));
        *reinterpret_cast<uint4*>(&As[srow][spart]) = *(const uint4*)us;
        const float* wsrc = &wf[(size_t)(c0 + srow) * 512 + kt + spart];
        float4 b0 = *(const float4*)wsrc, b1 = *(const float4*)(wsrc + 4);
        ushort4 ub0 = { f2bf(b0.x), f2bf(b0.y), f2bf(b0.z), f2bf(b0.w) };
        ushort4 ub1 = { f2bf(b1.x), f2bf(b1.y), f2bf(b1.z), f2bf(b1.w) };
        *(ushort4*)&Bs[srow][spart] = ub0; *(ushort4*)&Bs[srow][spart + 4] = ub1;
        __syncthreads();
        bf16x8 af[2], bfr[2];
        #pragma unroll
        for (int mf = 0; mf < 2; mf++) af[mf] = ld_bf8(&As[wr*32 + mf*16 + li][lg*8]);
        #pragma unroll
        for (int nf = 0; nf < 2; nf++) bfr[nf] = ld_bf8(&Bs[wc*32 + nf*16 + li][lg*8]);
        #pragma unroll
        for (int mf = 0; mf < 2; mf++)
            #pragma unroll
            for (int nf = 0; nf < 2; nf++)
                acc[mf][nf] = mfma16(af[mf], bfr[nf], acc[mf][nf]);
        __syncthreads();
    }
    #pragma unroll
    for (int mf = 0; mf < 2; mf++)
        #pragma unroll
        for (int nf = 0; nf < 2; nf++)
            #pragma unroll
            for (int r = 0; r < 4; r++) {
                int grow = m0 + wr*32 + mf*16 + lg*4 + r;
                int gcol = c0 + wc*32 + nf*16 + li;
                out[(size_t)grow * 512 + gcol] = acc[mf][nf][r] + bias[gcol];
            }
}

extern "C" void kernel_launch(void* const* d_in, const int* in_sizes, int n_in,
                              void* d_out, int out_size, void* d_ws, size_t ws_size,
                              hipStream_t stream)
{
    const float* x      = (const float*)d_in[0];
    const float* w_qkv  = (const float*)d_in[1];
    const float* b_qkv  = (const float*)d_in[2];
    const float* w_pre  = (const float*)d_in[3];
    const float* w_post = (const float*)d_in[4];
    const float* w_out  = (const float*)d_in[5];
    const float* b_out  = (const float*)d_in[6];
    float* out = (float*)d_out;

    char* ws = (char*)d_ws;
    unsigned short* Qb   = (unsigned short*)(ws);               // 4 MB
    unsigned short* Kb   = (unsigned short*)(ws + 4194304);     // 4 MB
    unsigned short* Vt   = (unsigned short*)(ws + 8388608);     // 4 MB
    unsigned short* AOp0 = (unsigned short*)(ws + 12582912);    // 4 MB
    unsigned short* AOp1 = (unsigned short*)(ws + 16777216);    // 4 MB
    float* Lp            = (float*)(ws + 20971520);             // 256 KB

    k_qkv<<<dim3(64, 24), 256, 0, stream>>>(x, w_qkv, b_qkv, Qb, Kb, Vt);
    k_lsum<<<512, 512, 0, stream>>>(Qb, Kb, w_pre, Lp);
    k_attn<<<512, 512, 0, stream>>>(Qb, Kb, Vt, w_pre, w_post, Lp, AOp0, AOp1);
    k_out<<<dim3(64, 8), 256, 0, stream>>>(AOp0, AOp1, w_out, b_out, out);
}